// Round 14
// baseline (244.327 us; speedup 1.0000x reference)
//
#include <hip/hip_runtime.h>
#include <float.h>
#include <math.h>

#define NNODES 100000
#define NEDGES 800000
#define NF 128
#define NCLASSES 10
#define NGRAPHS 256

#define NBIN 98              // ceil(100000 / 1024) dst-bins of 1024 nodes
#define BCHUNK 4096          // edges per block in binct/binscatter
#define NB2 196              // ceil(NEDGES / BCHUNK)
#define CNTS_PAD 20480       // NBIN*NB2 = 19208, padded to 10*2048 for the scan
#define SCAN_CHUNK 2048

typedef __attribute__((ext_vector_type(8))) short bf16x8;
typedef __attribute__((ext_vector_type(4))) float f32x4;

__device__ inline ushort f2bf(float f) {  // fp32 -> bf16 RNE
    unsigned u = __float_as_uint(f);
    u = u + 0x7FFFu + ((u >> 16) & 1u);
    return (ushort)(u >> 16);
}
__device__ inline float b2f(ushort h) {
    return __uint_as_float(((unsigned)h) << 16);
}
// unpack packed 2xbf16 word: lo and hi halves to fp32
__device__ inline void up2(unsigned u, float& lo, float& hi) {
    lo = __uint_as_float(u << 16);
    hi = __uint_as_float(u & 0xFFFF0000u);
}
// monotone fp32<->uint encoding: uint max order == float max order
__device__ inline unsigned fenc(float f) {
    unsigned u = __float_as_uint(f);
    return ((int)u < 0) ? ~u : (u | 0x80000000u);
}
__device__ inline float fdec(unsigned s) {
    return (s & 0x80000000u) ? __uint_as_float(s ^ 0x80000000u) : __uint_as_float(~s);
}

// ---------------- pass 1: per-(bin, block) edge counts ----------------
__global__ __launch_bounds__(256) void binct_kernel(const int* __restrict__ dst,
                                                    unsigned* __restrict__ cnts, int E) {
    __shared__ unsigned lh[NBIN];
    int tid = threadIdx.x;
    if (tid < NBIN) lh[tid] = 0;
    __syncthreads();
    int e0 = blockIdx.x * BCHUNK;
    int e1 = min(e0 + BCHUNK, E);
    for (int e = e0 + tid; e < e1; e += 256)
        atomicAdd(&lh[dst[e] >> 10], 1u);
    __syncthreads();
    if (tid < NBIN) cnts[tid * NB2 + blockIdx.x] = lh[tid];
}

// ---------------- small multi-block exclusive scan (N = CNTS_PAD) ----------------
__global__ __launch_bounds__(256) void scanA_kernel(const unsigned* __restrict__ cnt,
                                                    unsigned* __restrict__ bsum, int N) {
    __shared__ unsigned wsum[4];
    int tid = threadIdx.x, wid = tid >> 6, lane = tid & 63;
    int base = blockIdx.x * SCAN_CHUNK + tid * 8;
    unsigned s = 0;
    if (base < N) {
        uint4 a = *(const uint4*)(cnt + base);
        uint4 b = *(const uint4*)(cnt + base + 4);
        s = a.x + a.y + a.z + a.w + b.x + b.y + b.z + b.w;
    }
    #pragma unroll
    for (int off = 32; off >= 1; off >>= 1) s += __shfl_down(s, off, 64);
    if (lane == 0) wsum[wid] = s;
    __syncthreads();
    if (tid == 0) bsum[blockIdx.x] = wsum[0] + wsum[1] + wsum[2] + wsum[3];
}

__global__ __launch_bounds__(64) void scanB_kernel(const unsigned* __restrict__ bsum,
                                                   unsigned* __restrict__ boff, int nb) {
    int lane = threadIdx.x;
    unsigned v = (lane < nb) ? bsum[lane] : 0u;
    unsigned incl = v;
    #pragma unroll
    for (int off = 1; off < 64; off <<= 1) {
        unsigned t = __shfl_up(incl, off, 64);
        if (lane >= off) incl += t;
    }
    if (lane < nb) boff[lane] = incl - v;
}

__global__ __launch_bounds__(256) void scanC_kernel(const unsigned* __restrict__ cnt,
                                                    const unsigned* __restrict__ boff,
                                                    unsigned* __restrict__ outp, int N) {
    __shared__ unsigned wsum[4];
    int tid = threadIdx.x, wid = tid >> 6, lane = tid & 63;
    int base = blockIdx.x * SCAN_CHUNK + tid * 8;
    unsigned v[8];
    unsigned s = 0;
    bool act = base < N;
    if (act) {
        uint4 a = *(const uint4*)(cnt + base);
        uint4 b = *(const uint4*)(cnt + base + 4);
        v[0] = a.x; v[1] = a.y; v[2] = a.z; v[3] = a.w;
        v[4] = b.x; v[5] = b.y; v[6] = b.z; v[7] = b.w;
        #pragma unroll
        for (int j = 0; j < 8; ++j) s += v[j];
    }
    unsigned incl = s;
    #pragma unroll
    for (int off = 1; off < 64; off <<= 1) {
        unsigned t = __shfl_up(incl, off, 64);
        if (lane >= off) incl += t;
    }
    if (lane == 63) wsum[wid] = incl;
    __syncthreads();
    unsigned woff = 0;
    for (int w = 0; w < 4; ++w) if (w < wid) woff += wsum[w];
    if (act) {
        unsigned run = incl - s + woff + boff[blockIdx.x];
        #pragma unroll
        for (int j = 0; j < 8; ++j) {
            outp[base + j] = run;
            run += v[j];
        }
    }
}

// ---------------- pass 3: scatter edges bin-contiguously (LDS cursors, no global atomics) ----------------
__global__ __launch_bounds__(256) void binscatter_kernel(const int* __restrict__ src,
                                                         const int* __restrict__ dst,
                                                         const unsigned* __restrict__ offs,
                                                         unsigned* __restrict__ bedge, int E) {
    __shared__ unsigned lcur[NBIN];
    int tid = threadIdx.x;
    if (tid < NBIN) lcur[tid] = offs[tid * NB2 + blockIdx.x];
    __syncthreads();
    int e0 = blockIdx.x * BCHUNK;
    int e1 = min(e0 + BCHUNK, E);
    for (int e = e0 + tid; e < e1; e += 256) {
        int d = dst[e];
        int b = d >> 10;
        unsigned pos = atomicAdd(&lcur[b], 1u);
        bedge[pos] = ((unsigned)src[e] << 10) | (unsigned)(d & 1023);
    }
}

// ---------------- pass 4: per-bin node counts -> rowptr, dinv, csr placement ----------------
__global__ __launch_bounds__(256) void bucket_kernel(const unsigned* __restrict__ bedge,
                                                     const unsigned* __restrict__ offs,
                                                     float* __restrict__ dinv,
                                                     unsigned* __restrict__ rowptr,
                                                     unsigned* __restrict__ csr_src, int N) {
    __shared__ unsigned lcnt[1024];
    __shared__ unsigned lcur[1024];
    __shared__ unsigned wsum[4];
    int b = blockIdx.x;
    int tid = threadIdx.x, wid = tid >> 6, lane = tid & 63;
    unsigned ebeg = offs[b * NB2], eend = offs[(b + 1) * NB2];
    lcnt[tid] = 0; lcnt[tid + 256] = 0; lcnt[tid + 512] = 0; lcnt[tid + 768] = 0;
    __syncthreads();
    for (unsigned e = ebeg + tid; e < eend; e += 256)
        atomicAdd(&lcnt[bedge[e] & 1023], 1u);
    __syncthreads();
    unsigned c[4];
    unsigned s = 0;
    #pragma unroll
    for (int j = 0; j < 4; ++j) { c[j] = lcnt[tid * 4 + j]; s += c[j]; }
    unsigned incl = s;
    #pragma unroll
    for (int off = 1; off < 64; off <<= 1) {
        unsigned t = __shfl_up(incl, off, 64);
        if (lane >= off) incl += t;
    }
    if (lane == 63) wsum[wid] = incl;
    __syncthreads();
    unsigned woff = 0;
    for (int w = 0; w < 4; ++w) if (w < wid) woff += wsum[w];
    unsigned run = (incl - s) + woff + ebeg;
    int gbase = b * 1024 + tid * 4;
    #pragma unroll
    for (int j = 0; j < 4; ++j) {
        if (gbase + j < N) {
            rowptr[gbase + j] = run;
            dinv[gbase + j] = rsqrtf((float)c[j] + 1.0f);
        }
        lcur[tid * 4 + j] = run;
        run += c[j];
    }
    if (b == NBIN - 1 && tid == 0) rowptr[N] = eend;
    __syncthreads();
    for (unsigned e = ebeg + tid; e < eend; e += 256) {
        unsigned v = bedge[e];
        unsigned pos = atomicAdd(&lcur[v & 1023], 1u);
        csr_src[pos] = v >> 10;
    }
}

// ---------------- W -> lane-ordered bf16 MFMA fragments ----------------
__global__ __launch_bounds__(256) void wprep_kernel(const float* __restrict__ Ws,
                                                    short* __restrict__ Wf) {
    int l = blockIdx.x;
    for (int idx = threadIdx.x; idx < 16384; idx += 256) {
        int i = idx & 7;
        int lane = (idx >> 3) & 63;
        int ns = idx >> 9;
        int s = ns & 3, nt = ns >> 2;
        int k = s * 32 + (lane >> 4) * 8 + i;
        int n = nt * 16 + (lane & 15);
        Wf[l * 16384 + idx] = (short)f2bf(Ws[l * 16384 + k * NF + n]);
    }
}

// ---------------- H = X @ W via bf16 MFMA; C repacked through LDS -> uint4 stores ---------
template<bool L0>
__global__ __launch_bounds__(256) void gemm_mfma_kernel(const void* __restrict__ Xin,
                                                        const short* __restrict__ Wf,
                                                        ushort* __restrict__ Hb, int M) {
    __shared__ short Wl[16384];   // 32 KB: W fragments, then reused as the C tile
    int tid = threadIdx.x;
    for (int i = tid; i < 2048; i += 256)
        ((float4*)Wl)[i] = ((const float4*)Wf)[i];

    int wave = tid >> 6, lane = tid & 63;
    int r = lane & 15, kg = lane >> 4;
    int rowbase = blockIdx.x * 128 + wave * 32;

    bf16x8 afrag[2][4];
    #pragma unroll
    for (int t = 0; t < 2; ++t) {
        #pragma unroll
        for (int s = 0; s < 4; ++s) {
            int row = rowbase + t * 16 + r;
            if (row > M - 1) row = M - 1;
            if (L0) {
                const float* p = (const float*)Xin + (size_t)row * NF + s * 32 + kg * 8;
                float4 u0 = *(const float4*)p;
                float4 u1 = *(const float4*)(p + 4);
                bf16x8 a;
                a[0] = (short)f2bf(u0.x); a[1] = (short)f2bf(u0.y);
                a[2] = (short)f2bf(u0.z); a[3] = (short)f2bf(u0.w);
                a[4] = (short)f2bf(u1.x); a[5] = (short)f2bf(u1.y);
                a[6] = (short)f2bf(u1.z); a[7] = (short)f2bf(u1.w);
                afrag[t][s] = a;
            } else {
                afrag[t][s] = *(const bf16x8*)((const ushort*)Xin + (size_t)row * NF + s * 32 + kg * 8);
            }
        }
    }

    f32x4 acc[2][8];
    #pragma unroll
    for (int t = 0; t < 2; ++t)
        #pragma unroll
        for (int n = 0; n < 8; ++n)
            acc[t][n] = (f32x4){0.f, 0.f, 0.f, 0.f};

    __syncthreads();
    const bf16x8* WL = (const bf16x8*)Wl;
    #pragma unroll
    for (int s = 0; s < 4; ++s) {
        #pragma unroll
        for (int n = 0; n < 8; ++n) {
            bf16x8 bfr = WL[(n * 4 + s) * 64 + lane];
            acc[0][n] = __builtin_amdgcn_mfma_f32_16x16x32_bf16(afrag[0][s], bfr, acc[0][n], 0, 0, 0);
            acc[1][n] = __builtin_amdgcn_mfma_f32_16x16x32_bf16(afrag[1][s], bfr, acc[1][n], 0, 0, 0);
        }
    }

    // repack C through LDS (Wl is dead after the MFMA loop)
    __syncthreads();
    ushort* Cl = (ushort*)Wl;     // [128 rows][128 cols] bf16 = 32 KB
    int r4 = kg * 4;
    #pragma unroll
    for (int t = 0; t < 2; ++t) {
        #pragma unroll
        for (int n = 0; n < 8; ++n) {
            #pragma unroll
            for (int q = 0; q < 4; ++q) {
                Cl[(wave * 32 + t * 16 + r4 + q) * NF + n * 16 + r] = f2bf(acc[t][n][q]);
            }
        }
    }
    __syncthreads();
    // coalesced store: 2048 x 16B chunks; lane-consecutive chunks -> 1KB/wave-instr
    int row0 = blockIdx.x * 128;
    #pragma unroll
    for (int k = 0; k < 8; ++k) {
        int c = k * 256 + tid;
        int row = row0 + (c >> 4);
        if (row < M)
            ((uint4*)Hb)[(size_t)row * 16 + (c & 15)] = ((const uint4*)Cl)[c];
    }
}

// ---- shared 8-edge gather step (bit-identical sequential fmaf order) ----
#define AGG_EDGE(gv, nv)                                              \
    up2(gv.x, t0, t1); a0 = fmaf(t0, nv, a0); a1 = fmaf(t1, nv, a1);  \
    up2(gv.y, t0, t1); a2 = fmaf(t0, nv, a2); a3 = fmaf(t1, nv, a3);  \
    up2(gv.z, t0, t1); a4 = fmaf(t0, nv, a4); a5 = fmaf(t1, nv, a5);  \
    up2(gv.w, t0, t1); a6 = fmaf(t0, nv, a6); a7 = fmaf(t1, nv, a7);

// ---------------- aggregate: 16 lanes/node, 16B/lane, 8-wide MLP unroll, LDS=0 ----------
// 256 thr = 16 nodes/block; 6250 blocks exactly (no tail).
__global__ __launch_bounds__(256) void aggregate_kernel(const ushort* __restrict__ Hb,
                                                        const float* __restrict__ dinv,
                                                        const unsigned* __restrict__ rowptr,
                                                        const unsigned* __restrict__ csr_src,
                                                        const float* __restrict__ bias,
                                                        ushort* __restrict__ Xout, int N) {
    int gid = blockIdx.x * 256 + threadIdx.x;
    int node = gid >> 4;
    int lane = gid & 15;
    int c0 = lane * 8;
    float di = dinv[node];
    float sl = di * di;
    float4 b0 = ((const float4*)bias)[lane * 2 + 0];
    float4 b1 = ((const float4*)bias)[lane * 2 + 1];
    uint4 hv = *(const uint4*)(Hb + (size_t)node * NF + c0);
    float a0, a1, a2, a3, a4, a5, a6, a7, t0, t1;
    up2(hv.x, t0, t1); a0 = fmaf(t0, sl, b0.x); a1 = fmaf(t1, sl, b0.y);
    up2(hv.y, t0, t1); a2 = fmaf(t0, sl, b0.z); a3 = fmaf(t1, sl, b0.w);
    up2(hv.z, t0, t1); a4 = fmaf(t0, sl, b1.x); a5 = fmaf(t1, sl, b1.y);
    up2(hv.w, t0, t1); a6 = fmaf(t0, sl, b1.z); a7 = fmaf(t1, sl, b1.w);
    unsigned e = rowptr[node], end = rowptr[node + 1];
    for (; e + 8 <= end; e += 8) {
        unsigned s0 = csr_src[e + 0], s1 = csr_src[e + 1];
        unsigned s2 = csr_src[e + 2], s3 = csr_src[e + 3];
        unsigned s4 = csr_src[e + 4], s5 = csr_src[e + 5];
        unsigned s6 = csr_src[e + 6], s7 = csr_src[e + 7];
        float n0 = dinv[s0] * di, n1 = dinv[s1] * di;
        float n2 = dinv[s2] * di, n3 = dinv[s3] * di;
        float n4 = dinv[s4] * di, n5 = dinv[s5] * di;
        float n6 = dinv[s6] * di, n7 = dinv[s7] * di;
        uint4 g0 = *(const uint4*)(Hb + (size_t)s0 * NF + c0);
        uint4 g1 = *(const uint4*)(Hb + (size_t)s1 * NF + c0);
        uint4 g2 = *(const uint4*)(Hb + (size_t)s2 * NF + c0);
        uint4 g3 = *(const uint4*)(Hb + (size_t)s3 * NF + c0);
        uint4 g4 = *(const uint4*)(Hb + (size_t)s4 * NF + c0);
        uint4 g5 = *(const uint4*)(Hb + (size_t)s5 * NF + c0);
        uint4 g6 = *(const uint4*)(Hb + (size_t)s6 * NF + c0);
        uint4 g7 = *(const uint4*)(Hb + (size_t)s7 * NF + c0);
        AGG_EDGE(g0, n0) AGG_EDGE(g1, n1) AGG_EDGE(g2, n2) AGG_EDGE(g3, n3)
        AGG_EDGE(g4, n4) AGG_EDGE(g5, n5) AGG_EDGE(g6, n6) AGG_EDGE(g7, n7)
    }
    for (; e + 4 <= end; e += 4) {
        unsigned s0 = csr_src[e + 0], s1 = csr_src[e + 1];
        unsigned s2 = csr_src[e + 2], s3 = csr_src[e + 3];
        float n0 = dinv[s0] * di, n1 = dinv[s1] * di;
        float n2 = dinv[s2] * di, n3 = dinv[s3] * di;
        uint4 g0 = *(const uint4*)(Hb + (size_t)s0 * NF + c0);
        uint4 g1 = *(const uint4*)(Hb + (size_t)s1 * NF + c0);
        uint4 g2 = *(const uint4*)(Hb + (size_t)s2 * NF + c0);
        uint4 g3 = *(const uint4*)(Hb + (size_t)s3 * NF + c0);
        AGG_EDGE(g0, n0) AGG_EDGE(g1, n1) AGG_EDGE(g2, n2) AGG_EDGE(g3, n3)
    }
    for (; e < end; ++e) {
        unsigned s = csr_src[e];
        float nm = dinv[s] * di;
        uint4 g = *(const uint4*)(Hb + (size_t)s * NF + c0);
        AGG_EDGE(g, nm)
    }
    a0 = a0 > 0.f ? a0 : expm1f(a0);
    a1 = a1 > 0.f ? a1 : expm1f(a1);
    a2 = a2 > 0.f ? a2 : expm1f(a2);
    a3 = a3 > 0.f ? a3 : expm1f(a3);
    a4 = a4 > 0.f ? a4 : expm1f(a4);
    a5 = a5 > 0.f ? a5 : expm1f(a5);
    a6 = a6 > 0.f ? a6 : expm1f(a6);
    a7 = a7 > 0.f ? a7 : expm1f(a7);
    uint4 o;
    o.x = ((unsigned)f2bf(a1) << 16) | f2bf(a0);
    o.y = ((unsigned)f2bf(a3) << 16) | f2bf(a2);
    o.z = ((unsigned)f2bf(a5) << 16) | f2bf(a4);
    o.w = ((unsigned)f2bf(a7) << 16) | f2bf(a6);
    *(uint4*)(Xout + (size_t)node * NF + c0) = o;
}

// ---------------- last-layer aggregate with fused global max pool ----------------
// 16 nodes/block (sorted batch) -> <= 16 graphs per block -> 16 LDS slots, no fallback.
__global__ __launch_bounds__(256) void aggregate_pool_kernel(const ushort* __restrict__ Hb,
                                                             const float* __restrict__ dinv,
                                                             const unsigned* __restrict__ rowptr,
                                                             const unsigned* __restrict__ csr_src,
                                                             const float* __restrict__ bias,
                                                             const int* __restrict__ batch,
                                                             unsigned* __restrict__ Gx, int N) {
    __shared__ unsigned lmax[16][NF];   // 8 KB
    __shared__ int g0s;
    int tid = threadIdx.x;
    int gid = blockIdx.x * 256 + tid;
    int node = gid >> 4;
    int lane = gid & 15;
    int c0 = lane * 8;
    for (int i = tid; i < 16 * NF; i += 256) ((unsigned*)lmax)[i] = 0;
    if (tid == 0) g0s = batch[blockIdx.x * 16];
    __syncthreads();
    float di = dinv[node];
    float sl = di * di;
    float4 b0 = ((const float4*)bias)[lane * 2 + 0];
    float4 b1 = ((const float4*)bias)[lane * 2 + 1];
    uint4 hv = *(const uint4*)(Hb + (size_t)node * NF + c0);
    float a0, a1, a2, a3, a4, a5, a6, a7, t0, t1;
    up2(hv.x, t0, t1); a0 = fmaf(t0, sl, b0.x); a1 = fmaf(t1, sl, b0.y);
    up2(hv.y, t0, t1); a2 = fmaf(t0, sl, b0.z); a3 = fmaf(t1, sl, b0.w);
    up2(hv.z, t0, t1); a4 = fmaf(t0, sl, b1.x); a5 = fmaf(t1, sl, b1.y);
    up2(hv.w, t0, t1); a6 = fmaf(t0, sl, b1.z); a7 = fmaf(t1, sl, b1.w);
    unsigned e = rowptr[node], end = rowptr[node + 1];
    for (; e + 8 <= end; e += 8) {
        unsigned s0 = csr_src[e + 0], s1 = csr_src[e + 1];
        unsigned s2 = csr_src[e + 2], s3 = csr_src[e + 3];
        unsigned s4 = csr_src[e + 4], s5 = csr_src[e + 5];
        unsigned s6 = csr_src[e + 6], s7 = csr_src[e + 7];
        float n0 = dinv[s0] * di, n1 = dinv[s1] * di;
        float n2 = dinv[s2] * di, n3 = dinv[s3] * di;
        float n4 = dinv[s4] * di, n5 = dinv[s5] * di;
        float n6 = dinv[s6] * di, n7 = dinv[s7] * di;
        uint4 g0 = *(const uint4*)(Hb + (size_t)s0 * NF + c0);
        uint4 g1 = *(const uint4*)(Hb + (size_t)s1 * NF + c0);
        uint4 g2 = *(const uint4*)(Hb + (size_t)s2 * NF + c0);
        uint4 g3 = *(const uint4*)(Hb + (size_t)s3 * NF + c0);
        uint4 g4 = *(const uint4*)(Hb + (size_t)s4 * NF + c0);
        uint4 g5 = *(const uint4*)(Hb + (size_t)s5 * NF + c0);
        uint4 g6 = *(const uint4*)(Hb + (size_t)s6 * NF + c0);
        uint4 g7 = *(const uint4*)(Hb + (size_t)s7 * NF + c0);
        AGG_EDGE(g0, n0) AGG_EDGE(g1, n1) AGG_EDGE(g2, n2) AGG_EDGE(g3, n3)
        AGG_EDGE(g4, n4) AGG_EDGE(g5, n5) AGG_EDGE(g6, n6) AGG_EDGE(g7, n7)
    }
    for (; e + 4 <= end; e += 4) {
        unsigned s0 = csr_src[e + 0], s1 = csr_src[e + 1];
        unsigned s2 = csr_src[e + 2], s3 = csr_src[e + 3];
        float n0 = dinv[s0] * di, n1 = dinv[s1] * di;
        float n2 = dinv[s2] * di, n3 = dinv[s3] * di;
        uint4 g0 = *(const uint4*)(Hb + (size_t)s0 * NF + c0);
        uint4 g1 = *(const uint4*)(Hb + (size_t)s1 * NF + c0);
        uint4 g2 = *(const uint4*)(Hb + (size_t)s2 * NF + c0);
        uint4 g3 = *(const uint4*)(Hb + (size_t)s3 * NF + c0);
        AGG_EDGE(g0, n0) AGG_EDGE(g1, n1) AGG_EDGE(g2, n2) AGG_EDGE(g3, n3)
    }
    for (; e < end; ++e) {
        unsigned s = csr_src[e];
        float nm = dinv[s] * di;
        uint4 g = *(const uint4*)(Hb + (size_t)s * NF + c0);
        AGG_EDGE(g, nm)
    }
    a0 = a0 > 0.f ? a0 : expm1f(a0);
    a1 = a1 > 0.f ? a1 : expm1f(a1);
    a2 = a2 > 0.f ? a2 : expm1f(a2);
    a3 = a3 > 0.f ? a3 : expm1f(a3);
    a4 = a4 > 0.f ? a4 : expm1f(a4);
    a5 = a5 > 0.f ? a5 : expm1f(a5);
    a6 = a6 > 0.f ? a6 : expm1f(a6);
    a7 = a7 > 0.f ? a7 : expm1f(a7);
    int slot = batch[node] - g0s;      // < 16 by sortedness
    unsigned* lm = &lmax[slot][c0];
    atomicMax(lm + 0, fenc(a0)); atomicMax(lm + 1, fenc(a1));
    atomicMax(lm + 2, fenc(a2)); atomicMax(lm + 3, fenc(a3));
    atomicMax(lm + 4, fenc(a4)); atomicMax(lm + 5, fenc(a5));
    atomicMax(lm + 6, fenc(a6)); atomicMax(lm + 7, fenc(a7));
    __syncthreads();
    for (int i = tid; i < 16 * NF; i += 256) {
        unsigned v = ((unsigned*)lmax)[i];
        if (v) atomicMax(&Gx[(size_t)(g0s + (i >> 7)) * NF + (i & (NF - 1))], v);
    }
}

// ---------------- classifier: softmax(decode(Gx) @ Wc + bc), fp32 ----------------
__global__ __launch_bounds__(128) void classify_kernel(const unsigned* __restrict__ Gx,
                                                       const float* __restrict__ Wc,
                                                       const float* __restrict__ bc,
                                                       float* __restrict__ out) {
    __shared__ float gr[NF];
    __shared__ float lg[NCLASSES];
    int g = blockIdx.x;
    int tid = threadIdx.x;
    gr[tid] = fdec(Gx[(size_t)g * NF + tid]);
    __syncthreads();
    if (tid < NCLASSES) {
        float s = bc[tid];
        for (int k = 0; k < NF; ++k) s = fmaf(gr[k], Wc[k * NCLASSES + tid], s);
        lg[tid] = s;
    }
    __syncthreads();
    if (tid == 0) {
        float m = lg[0];
        #pragma unroll
        for (int c = 1; c < NCLASSES; ++c) m = fmaxf(m, lg[c]);
        float e[NCLASSES];
        float sum = 0.f;
        #pragma unroll
        for (int c = 0; c < NCLASSES; ++c) { e[c] = expf(lg[c] - m); sum += e[c]; }
        #pragma unroll
        for (int c = 0; c < NCLASSES; ++c) out[g * NCLASSES + c] = e[c] / sum;
    }
}

extern "C" void kernel_launch(void* const* d_in, const int* in_sizes, int n_in,
                              void* d_out, int out_size, void* d_ws, size_t ws_size,
                              hipStream_t stream) {
    const float* x     = (const float*)d_in[0];
    const int*   ei    = (const int*)d_in[1];
    const int*   batch = (const int*)d_in[2];
    const float* Ws    = (const float*)d_in[3];
    const float* bs    = (const float*)d_in[4];
    const float* Wc    = (const float*)d_in[5];
    const float* bc    = (const float*)d_in[6];
    float* out = (float*)d_out;

    const int* src = ei;
    const int* dst = ei + NEDGES;

    char* ws = (char*)d_ws;
    size_t off = 0;
    auto alloc = [&](size_t bytes) -> void* {
        off = (off + 255) & ~(size_t)255;
        void* p = ws + off;
        off += bytes;
        return p;
    };
    ushort*   B0      = (ushort*)alloc(sizeof(ushort) * (size_t)NNODES * NF);
    ushort*   B1      = (ushort*)alloc(sizeof(ushort) * (size_t)NNODES * NF);
    ushort*   Hb      = (ushort*)alloc(sizeof(ushort) * (size_t)NNODES * NF);
    float*    dinvp   = (float*)alloc(sizeof(float) * NNODES);
    unsigned* rowptr  = (unsigned*)alloc(sizeof(unsigned) * (NNODES + 1));
    unsigned* csr_src = (unsigned*)alloc(sizeof(unsigned) * NEDGES);
    unsigned* bedge   = (unsigned*)alloc(sizeof(unsigned) * NEDGES);
    unsigned* offs    = (unsigned*)alloc(sizeof(unsigned) * (CNTS_PAD + 1));
    unsigned* bsum    = (unsigned*)alloc(sizeof(unsigned) * 16);
    unsigned* boff    = (unsigned*)alloc(sizeof(unsigned) * 16);
    short*    Wf      = (short*)alloc(sizeof(short) * 3 * 16384);
    // zero-region: cnts + Gx contiguous -> single memset
    unsigned* cnts    = (unsigned*)alloc(sizeof(unsigned) * CNTS_PAD);
    unsigned* Gx      = (unsigned*)alloc(sizeof(unsigned) * NGRAPHS * NF);
    size_t zspan = (size_t)((char*)(Gx + NGRAPHS * NF) - (char*)cnts);

    hipMemsetAsync(cnts, 0, zspan, stream);
    wprep_kernel<<<3, 256, 0, stream>>>(Ws, Wf);
    binct_kernel<<<NB2, 256, 0, stream>>>(dst, cnts, NEDGES);
    scanA_kernel<<<CNTS_PAD / SCAN_CHUNK, 256, 0, stream>>>(cnts, bsum, CNTS_PAD);
    scanB_kernel<<<1, 64, 0, stream>>>(bsum, boff, CNTS_PAD / SCAN_CHUNK);
    scanC_kernel<<<CNTS_PAD / SCAN_CHUNK, 256, 0, stream>>>(cnts, boff, offs, CNTS_PAD);
    binscatter_kernel<<<NB2, 256, 0, stream>>>(src, dst, offs, bedge, NEDGES);
    bucket_kernel<<<NBIN, 256, 0, stream>>>(bedge, offs, dinvp, rowptr, csr_src, NNODES);

    int gemm_grid = (NNODES + 127) / 128;   // 782
    int agg_grid  = NNODES / 16;            // 6250 exact (16 nodes/block, 16 lanes/node)

    gemm_mfma_kernel<true><<<gemm_grid, 256, 0, stream>>>(x, Wf + 0 * 16384, Hb, NNODES);
    aggregate_kernel<<<agg_grid, 256, 0, stream>>>(Hb, dinvp, rowptr, csr_src,
                                                   bs + 0 * NF, B1, NNODES);
    gemm_mfma_kernel<false><<<gemm_grid, 256, 0, stream>>>(B1, Wf + 1 * 16384, Hb, NNODES);
    aggregate_kernel<<<agg_grid, 256, 0, stream>>>(Hb, dinvp, rowptr, csr_src,
                                                   bs + 1 * NF, B0, NNODES);
    gemm_mfma_kernel<false><<<gemm_grid, 256, 0, stream>>>(B0, Wf + 2 * 16384, Hb, NNODES);
    aggregate_pool_kernel<<<agg_grid, 256, 0, stream>>>(Hb, dinvp, rowptr, csr_src,
                                                        bs + 2 * NF, batch, Gx, NNODES);

    classify_kernel<<<NGRAPHS, 128, 0, stream>>>(Gx, Wc, bc, out);
}

// Round 15
// 229.460 us; speedup vs baseline: 1.0648x; 1.0648x over previous
//
#include <hip/hip_runtime.h>
#include <float.h>
#include <math.h>

#define NNODES 100000
#define NEDGES 800000
#define NF 128
#define NCLASSES 10
#define NGRAPHS 256

#define NBIN 98              // ceil(100000 / 1024) dst-bins of 1024 nodes
#define BCHUNK 4096          // edges per block in binct/binscatter
#define NB2 196              // ceil(NEDGES / BCHUNK)
#define CNTS_PAD 20480       // NBIN*NB2 = 19208, padded to 10*2048 for the scan
#define SCAN_CHUNK 2048

typedef __attribute__((ext_vector_type(8))) short bf16x8;
typedef __attribute__((ext_vector_type(4))) float f32x4;

__device__ inline ushort f2bf(float f) {  // fp32 -> bf16 RNE
    unsigned u = __float_as_uint(f);
    u = u + 0x7FFFu + ((u >> 16) & 1u);
    return (ushort)(u >> 16);
}
__device__ inline float b2f(ushort h) {
    return __uint_as_float(((unsigned)h) << 16);
}
// unpack packed 2xbf16 word: lo and hi halves to fp32
__device__ inline void up2(unsigned u, float& lo, float& hi) {
    lo = __uint_as_float(u << 16);
    hi = __uint_as_float(u & 0xFFFF0000u);
}
// monotone fp32<->uint encoding: uint max order == float max order
__device__ inline unsigned fenc(float f) {
    unsigned u = __float_as_uint(f);
    return ((int)u < 0) ? ~u : (u | 0x80000000u);
}
__device__ inline float fdec(unsigned s) {
    return (s & 0x80000000u) ? __uint_as_float(s ^ 0x80000000u) : __uint_as_float(~s);
}

// ---------------- pass 1: per-(bin, block) edge counts ----------------
__global__ __launch_bounds__(256) void binct_kernel(const int* __restrict__ dst,
                                                    unsigned* __restrict__ cnts, int E) {
    __shared__ unsigned lh[NBIN];
    int tid = threadIdx.x;
    if (tid < NBIN) lh[tid] = 0;
    __syncthreads();
    int e0 = blockIdx.x * BCHUNK;
    int e1 = min(e0 + BCHUNK, E);
    for (int e = e0 + tid; e < e1; e += 256)
        atomicAdd(&lh[dst[e] >> 10], 1u);
    __syncthreads();
    if (tid < NBIN) cnts[tid * NB2 + blockIdx.x] = lh[tid];
}

// ---------------- small multi-block exclusive scan (N = CNTS_PAD) ----------------
__global__ __launch_bounds__(256) void scanA_kernel(const unsigned* __restrict__ cnt,
                                                    unsigned* __restrict__ bsum, int N) {
    __shared__ unsigned wsum[4];
    int tid = threadIdx.x, wid = tid >> 6, lane = tid & 63;
    int base = blockIdx.x * SCAN_CHUNK + tid * 8;
    unsigned s = 0;
    if (base < N) {
        uint4 a = *(const uint4*)(cnt + base);
        uint4 b = *(const uint4*)(cnt + base + 4);
        s = a.x + a.y + a.z + a.w + b.x + b.y + b.z + b.w;
    }
    #pragma unroll
    for (int off = 32; off >= 1; off >>= 1) s += __shfl_down(s, off, 64);
    if (lane == 0) wsum[wid] = s;
    __syncthreads();
    if (tid == 0) bsum[blockIdx.x] = wsum[0] + wsum[1] + wsum[2] + wsum[3];
}

__global__ __launch_bounds__(64) void scanB_kernel(const unsigned* __restrict__ bsum,
                                                   unsigned* __restrict__ boff, int nb) {
    int lane = threadIdx.x;
    unsigned v = (lane < nb) ? bsum[lane] : 0u;
    unsigned incl = v;
    #pragma unroll
    for (int off = 1; off < 64; off <<= 1) {
        unsigned t = __shfl_up(incl, off, 64);
        if (lane >= off) incl += t;
    }
    if (lane < nb) boff[lane] = incl - v;
}

__global__ __launch_bounds__(256) void scanC_kernel(const unsigned* __restrict__ cnt,
                                                    const unsigned* __restrict__ boff,
                                                    unsigned* __restrict__ outp, int N) {
    __shared__ unsigned wsum[4];
    int tid = threadIdx.x, wid = tid >> 6, lane = tid & 63;
    int base = blockIdx.x * SCAN_CHUNK + tid * 8;
    unsigned v[8];
    unsigned s = 0;
    bool act = base < N;
    if (act) {
        uint4 a = *(const uint4*)(cnt + base);
        uint4 b = *(const uint4*)(cnt + base + 4);
        v[0] = a.x; v[1] = a.y; v[2] = a.z; v[3] = a.w;
        v[4] = b.x; v[5] = b.y; v[6] = b.z; v[7] = b.w;
        #pragma unroll
        for (int j = 0; j < 8; ++j) s += v[j];
    }
    unsigned incl = s;
    #pragma unroll
    for (int off = 1; off < 64; off <<= 1) {
        unsigned t = __shfl_up(incl, off, 64);
        if (lane >= off) incl += t;
    }
    if (lane == 63) wsum[wid] = incl;
    __syncthreads();
    unsigned woff = 0;
    for (int w = 0; w < 4; ++w) if (w < wid) woff += wsum[w];
    if (act) {
        unsigned run = incl - s + woff + boff[blockIdx.x];
        #pragma unroll
        for (int j = 0; j < 8; ++j) {
            outp[base + j] = run;
            run += v[j];
        }
    }
}

// ---------------- pass 3: scatter edges bin-contiguously (LDS cursors, no global atomics) ----------------
__global__ __launch_bounds__(256) void binscatter_kernel(const int* __restrict__ src,
                                                         const int* __restrict__ dst,
                                                         const unsigned* __restrict__ offs,
                                                         unsigned* __restrict__ bedge, int E) {
    __shared__ unsigned lcur[NBIN];
    int tid = threadIdx.x;
    if (tid < NBIN) lcur[tid] = offs[tid * NB2 + blockIdx.x];
    __syncthreads();
    int e0 = blockIdx.x * BCHUNK;
    int e1 = min(e0 + BCHUNK, E);
    for (int e = e0 + tid; e < e1; e += 256) {
        int d = dst[e];
        int b = d >> 10;
        unsigned pos = atomicAdd(&lcur[b], 1u);
        bedge[pos] = ((unsigned)src[e] << 10) | (unsigned)(d & 1023);
    }
}

// ---------------- pass 4: per-bin node counts -> rowptr, dinv, csr placement ----------------
__global__ __launch_bounds__(256) void bucket_kernel(const unsigned* __restrict__ bedge,
                                                     const unsigned* __restrict__ offs,
                                                     float* __restrict__ dinv,
                                                     unsigned* __restrict__ rowptr,
                                                     unsigned* __restrict__ csr_src, int N) {
    __shared__ unsigned lcnt[1024];
    __shared__ unsigned lcur[1024];
    __shared__ unsigned wsum[4];
    int b = blockIdx.x;
    int tid = threadIdx.x, wid = tid >> 6, lane = tid & 63;
    unsigned ebeg = offs[b * NB2], eend = offs[(b + 1) * NB2];
    lcnt[tid] = 0; lcnt[tid + 256] = 0; lcnt[tid + 512] = 0; lcnt[tid + 768] = 0;
    __syncthreads();
    for (unsigned e = ebeg + tid; e < eend; e += 256)
        atomicAdd(&lcnt[bedge[e] & 1023], 1u);
    __syncthreads();
    unsigned c[4];
    unsigned s = 0;
    #pragma unroll
    for (int j = 0; j < 4; ++j) { c[j] = lcnt[tid * 4 + j]; s += c[j]; }
    unsigned incl = s;
    #pragma unroll
    for (int off = 1; off < 64; off <<= 1) {
        unsigned t = __shfl_up(incl, off, 64);
        if (lane >= off) incl += t;
    }
    if (lane == 63) wsum[wid] = incl;
    __syncthreads();
    unsigned woff = 0;
    for (int w = 0; w < 4; ++w) if (w < wid) woff += wsum[w];
    unsigned run = (incl - s) + woff + ebeg;
    int gbase = b * 1024 + tid * 4;
    #pragma unroll
    for (int j = 0; j < 4; ++j) {
        if (gbase + j < N) {
            rowptr[gbase + j] = run;
            dinv[gbase + j] = rsqrtf((float)c[j] + 1.0f);
        }
        lcur[tid * 4 + j] = run;
        run += c[j];
    }
    if (b == NBIN - 1 && tid == 0) rowptr[N] = eend;
    __syncthreads();
    for (unsigned e = ebeg + tid; e < eend; e += 256) {
        unsigned v = bedge[e];
        unsigned pos = atomicAdd(&lcur[v & 1023], 1u);
        csr_src[pos] = v >> 10;
    }
}

// ---------------- W -> lane-ordered bf16 MFMA fragments ----------------
__global__ __launch_bounds__(256) void wprep_kernel(const float* __restrict__ Ws,
                                                    short* __restrict__ Wf) {
    int l = blockIdx.x;
    for (int idx = threadIdx.x; idx < 16384; idx += 256) {
        int i = idx & 7;
        int lane = (idx >> 3) & 63;
        int ns = idx >> 9;
        int s = ns & 3, nt = ns >> 2;
        int k = s * 32 + (lane >> 4) * 8 + i;
        int n = nt * 16 + (lane & 15);
        Wf[l * 16384 + idx] = (short)f2bf(Ws[l * 16384 + k * NF + n]);
    }
}

// ---------------- H = X @ W via bf16 MFMA; C repacked through LDS -> uint4 stores ---------
template<bool L0>
__global__ __launch_bounds__(256) void gemm_mfma_kernel(const void* __restrict__ Xin,
                                                        const short* __restrict__ Wf,
                                                        ushort* __restrict__ Hb, int M) {
    __shared__ short Wl[16384];   // 32 KB: W fragments, then reused as the C tile
    int tid = threadIdx.x;
    for (int i = tid; i < 2048; i += 256)
        ((float4*)Wl)[i] = ((const float4*)Wf)[i];

    int wave = tid >> 6, lane = tid & 63;
    int r = lane & 15, kg = lane >> 4;
    int rowbase = blockIdx.x * 128 + wave * 32;

    bf16x8 afrag[2][4];
    #pragma unroll
    for (int t = 0; t < 2; ++t) {
        #pragma unroll
        for (int s = 0; s < 4; ++s) {
            int row = rowbase + t * 16 + r;
            if (row > M - 1) row = M - 1;
            if (L0) {
                const float* p = (const float*)Xin + (size_t)row * NF + s * 32 + kg * 8;
                float4 u0 = *(const float4*)p;
                float4 u1 = *(const float4*)(p + 4);
                bf16x8 a;
                a[0] = (short)f2bf(u0.x); a[1] = (short)f2bf(u0.y);
                a[2] = (short)f2bf(u0.z); a[3] = (short)f2bf(u0.w);
                a[4] = (short)f2bf(u1.x); a[5] = (short)f2bf(u1.y);
                a[6] = (short)f2bf(u1.z); a[7] = (short)f2bf(u1.w);
                afrag[t][s] = a;
            } else {
                afrag[t][s] = *(const bf16x8*)((const ushort*)Xin + (size_t)row * NF + s * 32 + kg * 8);
            }
        }
    }

    f32x4 acc[2][8];
    #pragma unroll
    for (int t = 0; t < 2; ++t)
        #pragma unroll
        for (int n = 0; n < 8; ++n)
            acc[t][n] = (f32x4){0.f, 0.f, 0.f, 0.f};

    __syncthreads();
    const bf16x8* WL = (const bf16x8*)Wl;
    #pragma unroll
    for (int s = 0; s < 4; ++s) {
        #pragma unroll
        for (int n = 0; n < 8; ++n) {
            bf16x8 bfr = WL[(n * 4 + s) * 64 + lane];
            acc[0][n] = __builtin_amdgcn_mfma_f32_16x16x32_bf16(afrag[0][s], bfr, acc[0][n], 0, 0, 0);
            acc[1][n] = __builtin_amdgcn_mfma_f32_16x16x32_bf16(afrag[1][s], bfr, acc[1][n], 0, 0, 0);
        }
    }

    // repack C through LDS (Wl is dead after the MFMA loop)
    __syncthreads();
    ushort* Cl = (ushort*)Wl;     // [128 rows][128 cols] bf16 = 32 KB
    int r4 = kg * 4;
    #pragma unroll
    for (int t = 0; t < 2; ++t) {
        #pragma unroll
        for (int n = 0; n < 8; ++n) {
            #pragma unroll
            for (int q = 0; q < 4; ++q) {
                Cl[(wave * 32 + t * 16 + r4 + q) * NF + n * 16 + r] = f2bf(acc[t][n][q]);
            }
        }
    }
    __syncthreads();
    // coalesced store: 2048 x 16B chunks; lane-consecutive chunks -> 1KB/wave-instr
    int row0 = blockIdx.x * 128;
    #pragma unroll
    for (int k = 0; k < 8; ++k) {
        int c = k * 256 + tid;
        int row = row0 + (c >> 4);
        if (row < M)
            ((uint4*)Hb)[(size_t)row * 16 + (c & 15)] = ((const uint4*)Cl)[c];
    }
}

// ---------------- aggregate: 16 lanes/node, 16B/lane (uint4 of 8 bf16), LDS=0 ----------
// 256 thr = 16 nodes/block; 6250 blocks exactly (no tail). 4-wide unroll (measured
// optimum: 8-wide raised VGPR 28->48, occupancy 66->48%, net loss).
__global__ __launch_bounds__(256) void aggregate_kernel(const ushort* __restrict__ Hb,
                                                        const float* __restrict__ dinv,
                                                        const unsigned* __restrict__ rowptr,
                                                        const unsigned* __restrict__ csr_src,
                                                        const float* __restrict__ bias,
                                                        ushort* __restrict__ Xout, int N) {
    int gid = blockIdx.x * 256 + threadIdx.x;
    int node = gid >> 4;
    int lane = gid & 15;
    int c0 = lane * 8;
    float di = dinv[node];
    float sl = di * di;
    float4 b0 = ((const float4*)bias)[lane * 2 + 0];
    float4 b1 = ((const float4*)bias)[lane * 2 + 1];
    uint4 hv = *(const uint4*)(Hb + (size_t)node * NF + c0);
    float a0, a1, a2, a3, a4, a5, a6, a7, t0, t1;
    up2(hv.x, t0, t1); a0 = fmaf(t0, sl, b0.x); a1 = fmaf(t1, sl, b0.y);
    up2(hv.y, t0, t1); a2 = fmaf(t0, sl, b0.z); a3 = fmaf(t1, sl, b0.w);
    up2(hv.z, t0, t1); a4 = fmaf(t0, sl, b1.x); a5 = fmaf(t1, sl, b1.y);
    up2(hv.w, t0, t1); a6 = fmaf(t0, sl, b1.z); a7 = fmaf(t1, sl, b1.w);
    unsigned e = rowptr[node], end = rowptr[node + 1];
    for (; e + 4 <= end; e += 4) {
        unsigned s0 = csr_src[e + 0], s1 = csr_src[e + 1];
        unsigned s2 = csr_src[e + 2], s3 = csr_src[e + 3];
        float n0 = dinv[s0] * di, n1 = dinv[s1] * di;
        float n2 = dinv[s2] * di, n3 = dinv[s3] * di;
        uint4 g0 = *(const uint4*)(Hb + (size_t)s0 * NF + c0);
        uint4 g1 = *(const uint4*)(Hb + (size_t)s1 * NF + c0);
        uint4 g2 = *(const uint4*)(Hb + (size_t)s2 * NF + c0);
        uint4 g3 = *(const uint4*)(Hb + (size_t)s3 * NF + c0);
        up2(g0.x, t0, t1); a0 = fmaf(t0, n0, a0); a1 = fmaf(t1, n0, a1);
        up2(g0.y, t0, t1); a2 = fmaf(t0, n0, a2); a3 = fmaf(t1, n0, a3);
        up2(g0.z, t0, t1); a4 = fmaf(t0, n0, a4); a5 = fmaf(t1, n0, a5);
        up2(g0.w, t0, t1); a6 = fmaf(t0, n0, a6); a7 = fmaf(t1, n0, a7);
        up2(g1.x, t0, t1); a0 = fmaf(t0, n1, a0); a1 = fmaf(t1, n1, a1);
        up2(g1.y, t0, t1); a2 = fmaf(t0, n1, a2); a3 = fmaf(t1, n1, a3);
        up2(g1.z, t0, t1); a4 = fmaf(t0, n1, a4); a5 = fmaf(t1, n1, a5);
        up2(g1.w, t0, t1); a6 = fmaf(t0, n1, a6); a7 = fmaf(t1, n1, a7);
        up2(g2.x, t0, t1); a0 = fmaf(t0, n2, a0); a1 = fmaf(t1, n2, a1);
        up2(g2.y, t0, t1); a2 = fmaf(t0, n2, a2); a3 = fmaf(t1, n2, a3);
        up2(g2.z, t0, t1); a4 = fmaf(t0, n2, a4); a5 = fmaf(t1, n2, a5);
        up2(g2.w, t0, t1); a6 = fmaf(t0, n2, a6); a7 = fmaf(t1, n2, a7);
        up2(g3.x, t0, t1); a0 = fmaf(t0, n3, a0); a1 = fmaf(t1, n3, a1);
        up2(g3.y, t0, t1); a2 = fmaf(t0, n3, a2); a3 = fmaf(t1, n3, a3);
        up2(g3.z, t0, t1); a4 = fmaf(t0, n3, a4); a5 = fmaf(t1, n3, a5);
        up2(g3.w, t0, t1); a6 = fmaf(t0, n3, a6); a7 = fmaf(t1, n3, a7);
    }
    for (; e < end; ++e) {
        unsigned s = csr_src[e];
        float nm = dinv[s] * di;
        uint4 g = *(const uint4*)(Hb + (size_t)s * NF + c0);
        up2(g.x, t0, t1); a0 = fmaf(t0, nm, a0); a1 = fmaf(t1, nm, a1);
        up2(g.y, t0, t1); a2 = fmaf(t0, nm, a2); a3 = fmaf(t1, nm, a3);
        up2(g.z, t0, t1); a4 = fmaf(t0, nm, a4); a5 = fmaf(t1, nm, a5);
        up2(g.w, t0, t1); a6 = fmaf(t0, nm, a6); a7 = fmaf(t1, nm, a7);
    }
    a0 = a0 > 0.f ? a0 : expm1f(a0);
    a1 = a1 > 0.f ? a1 : expm1f(a1);
    a2 = a2 > 0.f ? a2 : expm1f(a2);
    a3 = a3 > 0.f ? a3 : expm1f(a3);
    a4 = a4 > 0.f ? a4 : expm1f(a4);
    a5 = a5 > 0.f ? a5 : expm1f(a5);
    a6 = a6 > 0.f ? a6 : expm1f(a6);
    a7 = a7 > 0.f ? a7 : expm1f(a7);
    uint4 o;
    o.x = ((unsigned)f2bf(a1) << 16) | f2bf(a0);
    o.y = ((unsigned)f2bf(a3) << 16) | f2bf(a2);
    o.z = ((unsigned)f2bf(a5) << 16) | f2bf(a4);
    o.w = ((unsigned)f2bf(a7) << 16) | f2bf(a6);
    *(uint4*)(Xout + (size_t)node * NF + c0) = o;
}

// ---------------- last-layer aggregate with fused global max pool ----------------
// 16 nodes/block; 4 LDS slots (block spans >4 graphs essentially never at ~390
// nodes/graph); rare slot>=4 falls back to device-scope atomicMax on Gx.
__global__ __launch_bounds__(256) void aggregate_pool_kernel(const ushort* __restrict__ Hb,
                                                             const float* __restrict__ dinv,
                                                             const unsigned* __restrict__ rowptr,
                                                             const unsigned* __restrict__ csr_src,
                                                             const float* __restrict__ bias,
                                                             const int* __restrict__ batch,
                                                             unsigned* __restrict__ Gx, int N) {
    __shared__ unsigned lmax[4][NF];   // 2 KB
    __shared__ int g0s;
    int tid = threadIdx.x;
    int gid = blockIdx.x * 256 + tid;
    int node = gid >> 4;
    int lane = gid & 15;
    int c0 = lane * 8;
    for (int i = tid; i < 4 * NF; i += 256) ((unsigned*)lmax)[i] = 0;
    if (tid == 0) g0s = batch[blockIdx.x * 16];
    __syncthreads();
    float di = dinv[node];
    float sl = di * di;
    float4 b0 = ((const float4*)bias)[lane * 2 + 0];
    float4 b1 = ((const float4*)bias)[lane * 2 + 1];
    uint4 hv = *(const uint4*)(Hb + (size_t)node * NF + c0);
    float a0, a1, a2, a3, a4, a5, a6, a7, t0, t1;
    up2(hv.x, t0, t1); a0 = fmaf(t0, sl, b0.x); a1 = fmaf(t1, sl, b0.y);
    up2(hv.y, t0, t1); a2 = fmaf(t0, sl, b0.z); a3 = fmaf(t1, sl, b0.w);
    up2(hv.z, t0, t1); a4 = fmaf(t0, sl, b1.x); a5 = fmaf(t1, sl, b1.y);
    up2(hv.w, t0, t1); a6 = fmaf(t0, sl, b1.z); a7 = fmaf(t1, sl, b1.w);
    unsigned e = rowptr[node], end = rowptr[node + 1];
    for (; e + 4 <= end; e += 4) {
        unsigned s0 = csr_src[e + 0], s1 = csr_src[e + 1];
        unsigned s2 = csr_src[e + 2], s3 = csr_src[e + 3];
        float n0 = dinv[s0] * di, n1 = dinv[s1] * di;
        float n2 = dinv[s2] * di, n3 = dinv[s3] * di;
        uint4 g0 = *(const uint4*)(Hb + (size_t)s0 * NF + c0);
        uint4 g1 = *(const uint4*)(Hb + (size_t)s1 * NF + c0);
        uint4 g2 = *(const uint4*)(Hb + (size_t)s2 * NF + c0);
        uint4 g3 = *(const uint4*)(Hb + (size_t)s3 * NF + c0);
        up2(g0.x, t0, t1); a0 = fmaf(t0, n0, a0); a1 = fmaf(t1, n0, a1);
        up2(g0.y, t0, t1); a2 = fmaf(t0, n0, a2); a3 = fmaf(t1, n0, a3);
        up2(g0.z, t0, t1); a4 = fmaf(t0, n0, a4); a5 = fmaf(t1, n0, a5);
        up2(g0.w, t0, t1); a6 = fmaf(t0, n0, a6); a7 = fmaf(t1, n0, a7);
        up2(g1.x, t0, t1); a0 = fmaf(t0, n1, a0); a1 = fmaf(t1, n1, a1);
        up2(g1.y, t0, t1); a2 = fmaf(t0, n1, a2); a3 = fmaf(t1, n1, a3);
        up2(g1.z, t0, t1); a4 = fmaf(t0, n1, a4); a5 = fmaf(t1, n1, a5);
        up2(g1.w, t0, t1); a6 = fmaf(t0, n1, a6); a7 = fmaf(t1, n1, a7);
        up2(g2.x, t0, t1); a0 = fmaf(t0, n2, a0); a1 = fmaf(t1, n2, a1);
        up2(g2.y, t0, t1); a2 = fmaf(t0, n2, a2); a3 = fmaf(t1, n2, a3);
        up2(g2.z, t0, t1); a4 = fmaf(t0, n2, a4); a5 = fmaf(t1, n2, a5);
        up2(g2.w, t0, t1); a6 = fmaf(t0, n2, a6); a7 = fmaf(t1, n2, a7);
        up2(g3.x, t0, t1); a0 = fmaf(t0, n3, a0); a1 = fmaf(t1, n3, a1);
        up2(g3.y, t0, t1); a2 = fmaf(t0, n3, a2); a3 = fmaf(t1, n3, a3);
        up2(g3.z, t0, t1); a4 = fmaf(t0, n3, a4); a5 = fmaf(t1, n3, a5);
        up2(g3.w, t0, t1); a6 = fmaf(t0, n3, a6); a7 = fmaf(t1, n3, a7);
    }
    for (; e < end; ++e) {
        unsigned s = csr_src[e];
        float nm = dinv[s] * di;
        uint4 g = *(const uint4*)(Hb + (size_t)s * NF + c0);
        up2(g.x, t0, t1); a0 = fmaf(t0, nm, a0); a1 = fmaf(t1, nm, a1);
        up2(g.y, t0, t1); a2 = fmaf(t0, nm, a2); a3 = fmaf(t1, nm, a3);
        up2(g.z, t0, t1); a4 = fmaf(t0, nm, a4); a5 = fmaf(t1, nm, a5);
        up2(g.w, t0, t1); a6 = fmaf(t0, nm, a6); a7 = fmaf(t1, nm, a7);
    }
    a0 = a0 > 0.f ? a0 : expm1f(a0);
    a1 = a1 > 0.f ? a1 : expm1f(a1);
    a2 = a2 > 0.f ? a2 : expm1f(a2);
    a3 = a3 > 0.f ? a3 : expm1f(a3);
    a4 = a4 > 0.f ? a4 : expm1f(a4);
    a5 = a5 > 0.f ? a5 : expm1f(a5);
    a6 = a6 > 0.f ? a6 : expm1f(a6);
    a7 = a7 > 0.f ? a7 : expm1f(a7);
    int slot = batch[node] - g0s;
    if (slot < 4) {
        unsigned* lm = &lmax[slot][c0];
        atomicMax(lm + 0, fenc(a0)); atomicMax(lm + 1, fenc(a1));
        atomicMax(lm + 2, fenc(a2)); atomicMax(lm + 3, fenc(a3));
        atomicMax(lm + 4, fenc(a4)); atomicMax(lm + 5, fenc(a5));
        atomicMax(lm + 6, fenc(a6)); atomicMax(lm + 7, fenc(a7));
    } else {  // rare: block spans >4 graphs
        unsigned* gm = &Gx[(size_t)(g0s + slot) * NF + c0];
        atomicMax(gm + 0, fenc(a0)); atomicMax(gm + 1, fenc(a1));
        atomicMax(gm + 2, fenc(a2)); atomicMax(gm + 3, fenc(a3));
        atomicMax(gm + 4, fenc(a4)); atomicMax(gm + 5, fenc(a5));
        atomicMax(gm + 6, fenc(a6)); atomicMax(gm + 7, fenc(a7));
    }
    __syncthreads();
    for (int i = tid; i < 4 * NF; i += 256) {
        unsigned v = ((unsigned*)lmax)[i];
        if (v) atomicMax(&Gx[(size_t)(g0s + (i >> 7)) * NF + (i & (NF - 1))], v);
    }
}

// ---------------- classifier: softmax(decode(Gx) @ Wc + bc), fp32 ----------------
__global__ __launch_bounds__(128) void classify_kernel(const unsigned* __restrict__ Gx,
                                                       const float* __restrict__ Wc,
                                                       const float* __restrict__ bc,
                                                       float* __restrict__ out) {
    __shared__ float gr[NF];
    __shared__ float lg[NCLASSES];
    int g = blockIdx.x;
    int tid = threadIdx.x;
    gr[tid] = fdec(Gx[(size_t)g * NF + tid]);
    __syncthreads();
    if (tid < NCLASSES) {
        float s = bc[tid];
        for (int k = 0; k < NF; ++k) s = fmaf(gr[k], Wc[k * NCLASSES + tid], s);
        lg[tid] = s;
    }
    __syncthreads();
    if (tid == 0) {
        float m = lg[0];
        #pragma unroll
        for (int c = 1; c < NCLASSES; ++c) m = fmaxf(m, lg[c]);
        float e[NCLASSES];
        float sum = 0.f;
        #pragma unroll
        for (int c = 0; c < NCLASSES; ++c) { e[c] = expf(lg[c] - m); sum += e[c]; }
        #pragma unroll
        for (int c = 0; c < NCLASSES; ++c) out[g * NCLASSES + c] = e[c] / sum;
    }
}

extern "C" void kernel_launch(void* const* d_in, const int* in_sizes, int n_in,
                              void* d_out, int out_size, void* d_ws, size_t ws_size,
                              hipStream_t stream) {
    const float* x     = (const float*)d_in[0];
    const int*   ei    = (const int*)d_in[1];
    const int*   batch = (const int*)d_in[2];
    const float* Ws    = (const float*)d_in[3];
    const float* bs    = (const float*)d_in[4];
    const float* Wc    = (const float*)d_in[5];
    const float* bc    = (const float*)d_in[6];
    float* out = (float*)d_out;

    const int* src = ei;
    const int* dst = ei + NEDGES;

    char* ws = (char*)d_ws;
    size_t off = 0;
    auto alloc = [&](size_t bytes) -> void* {
        off = (off + 255) & ~(size_t)255;
        void* p = ws + off;
        off += bytes;
        return p;
    };
    ushort*   B0      = (ushort*)alloc(sizeof(ushort) * (size_t)NNODES * NF);
    ushort*   B1      = (ushort*)alloc(sizeof(ushort) * (size_t)NNODES * NF);
    ushort*   Hb      = (ushort*)alloc(sizeof(ushort) * (size_t)NNODES * NF);
    float*    dinvp   = (float*)alloc(sizeof(float) * NNODES);
    unsigned* rowptr  = (unsigned*)alloc(sizeof(unsigned) * (NNODES + 1));
    unsigned* csr_src = (unsigned*)alloc(sizeof(unsigned) * NEDGES);
    unsigned* bedge   = (unsigned*)alloc(sizeof(unsigned) * NEDGES);
    unsigned* offs    = (unsigned*)alloc(sizeof(unsigned) * (CNTS_PAD + 1));
    unsigned* bsum    = (unsigned*)alloc(sizeof(unsigned) * 16);
    unsigned* boff    = (unsigned*)alloc(sizeof(unsigned) * 16);
    short*    Wf      = (short*)alloc(sizeof(short) * 3 * 16384);
    // zero-region: cnts + Gx contiguous -> single memset
    unsigned* cnts    = (unsigned*)alloc(sizeof(unsigned) * CNTS_PAD);
    unsigned* Gx      = (unsigned*)alloc(sizeof(unsigned) * NGRAPHS * NF);
    size_t zspan = (size_t)((char*)(Gx + NGRAPHS * NF) - (char*)cnts);

    hipMemsetAsync(cnts, 0, zspan, stream);
    wprep_kernel<<<3, 256, 0, stream>>>(Ws, Wf);
    binct_kernel<<<NB2, 256, 0, stream>>>(dst, cnts, NEDGES);
    scanA_kernel<<<CNTS_PAD / SCAN_CHUNK, 256, 0, stream>>>(cnts, bsum, CNTS_PAD);
    scanB_kernel<<<1, 64, 0, stream>>>(bsum, boff, CNTS_PAD / SCAN_CHUNK);
    scanC_kernel<<<CNTS_PAD / SCAN_CHUNK, 256, 0, stream>>>(cnts, boff, offs, CNTS_PAD);
    binscatter_kernel<<<NB2, 256, 0, stream>>>(src, dst, offs, bedge, NEDGES);
    bucket_kernel<<<NBIN, 256, 0, stream>>>(bedge, offs, dinvp, rowptr, csr_src, NNODES);

    int gemm_grid = (NNODES + 127) / 128;   // 782
    int agg_grid  = NNODES / 16;            // 6250 exact (16 nodes/block, 16 lanes/node)

    gemm_mfma_kernel<true><<<gemm_grid, 256, 0, stream>>>(x, Wf + 0 * 16384, Hb, NNODES);
    aggregate_kernel<<<agg_grid, 256, 0, stream>>>(Hb, dinvp, rowptr, csr_src,
                                                   bs + 0 * NF, B1, NNODES);
    gemm_mfma_kernel<false><<<gemm_grid, 256, 0, stream>>>(B1, Wf + 1 * 16384, Hb, NNODES);
    aggregate_kernel<<<agg_grid, 256, 0, stream>>>(Hb, dinvp, rowptr, csr_src,
                                                   bs + 1 * NF, B0, NNODES);
    gemm_mfma_kernel<false><<<gemm_grid, 256, 0, stream>>>(B0, Wf + 2 * 16384, Hb, NNODES);
    aggregate_pool_kernel<<<agg_grid, 256, 0, stream>>>(Hb, dinvp, rowptr, csr_src,
                                                        bs + 2 * NF, batch, Gx, NNODES);

    classify_kernel<<<NGRAPHS, 128, 0, stream>>>(Gx, Wc, bc, out);
}

// Round 16
// 225.386 us; speedup vs baseline: 1.0840x; 1.0181x over previous
//
#include <hip/hip_runtime.h>
#include <float.h>
#include <math.h>

#define NNODES 100000
#define NEDGES 800000
#define NF 128
#define NCLASSES 10
#define NGRAPHS 256

#define NBIN 98              // ceil(100000 / 1024) dst-bins of 1024 nodes
#define BCHUNK 4096          // edges per block in binct/binscatter
#define NB2 196              // ceil(NEDGES / BCHUNK)
#define CNTS_PAD 20480       // NBIN*NB2 = 19208, padded to 10*2048 for the scan
#define PADZ (CNTS_PAD - NBIN * NB2)   // 1272 pad words needing zero
#define SCAN_CHUNK 2048

typedef __attribute__((ext_vector_type(8))) short bf16x8;
typedef __attribute__((ext_vector_type(4))) float f32x4;

__device__ inline ushort f2bf(float f) {  // fp32 -> bf16 RNE
    unsigned u = __float_as_uint(f);
    u = u + 0x7FFFu + ((u >> 16) & 1u);
    return (ushort)(u >> 16);
}
__device__ inline float b2f(ushort h) {
    return __uint_as_float(((unsigned)h) << 16);
}
// unpack packed 2xbf16 word: lo and hi halves to fp32
__device__ inline void up2(unsigned u, float& lo, float& hi) {
    lo = __uint_as_float(u << 16);
    hi = __uint_as_float(u & 0xFFFF0000u);
}
// monotone fp32<->uint encoding: uint max order == float max order
__device__ inline unsigned fenc(float f) {
    unsigned u = __float_as_uint(f);
    return ((int)u < 0) ? ~u : (u | 0x80000000u);
}
__device__ inline float fdec(unsigned s) {
    return (s & 0x80000000u) ? __uint_as_float(s ^ 0x80000000u) : __uint_as_float(~s);
}

// ---------------- pass 1: per-(bin, block) edge counts + zero pad/Gx ----------------
// First kernel in the stream: also zeroes the scan pad region and Gx (replaces the
// 40us hipMemsetAsync dispatch). Consumers (scanA, aggregate_pool) are stream-ordered
// after this kernel completes; both regions are rewritten every call (deterministic).
__global__ __launch_bounds__(256) void binct_kernel(const int* __restrict__ dst,
                                                    unsigned* __restrict__ cnts,
                                                    unsigned* __restrict__ Gx, int E) {
    __shared__ unsigned lh[NBIN];
    int tid = threadIdx.x;
    // grid-stride zero of cnts pad + Gx (34040 words; 50176 threads -> one pass)
    for (int i = blockIdx.x * 256 + tid; i < PADZ + NGRAPHS * NF; i += gridDim.x * 256) {
        if (i < PADZ) cnts[NBIN * NB2 + i] = 0u;
        else Gx[i - PADZ] = 0u;
    }
    if (tid < NBIN) lh[tid] = 0;
    __syncthreads();
    int e0 = blockIdx.x * BCHUNK;
    int e1 = min(e0 + BCHUNK, E);
    for (int e = e0 + tid; e < e1; e += 256)
        atomicAdd(&lh[dst[e] >> 10], 1u);
    __syncthreads();
    if (tid < NBIN) cnts[tid * NB2 + blockIdx.x] = lh[tid];
}

// ---------------- small multi-block exclusive scan (N = CNTS_PAD) ----------------
__global__ __launch_bounds__(256) void scanA_kernel(const unsigned* __restrict__ cnt,
                                                    unsigned* __restrict__ bsum, int N) {
    __shared__ unsigned wsum[4];
    int tid = threadIdx.x, wid = tid >> 6, lane = tid & 63;
    int base = blockIdx.x * SCAN_CHUNK + tid * 8;
    unsigned s = 0;
    if (base < N) {
        uint4 a = *(const uint4*)(cnt + base);
        uint4 b = *(const uint4*)(cnt + base + 4);
        s = a.x + a.y + a.z + a.w + b.x + b.y + b.z + b.w;
    }
    #pragma unroll
    for (int off = 32; off >= 1; off >>= 1) s += __shfl_down(s, off, 64);
    if (lane == 0) wsum[wid] = s;
    __syncthreads();
    if (tid == 0) bsum[blockIdx.x] = wsum[0] + wsum[1] + wsum[2] + wsum[3];
}

__global__ __launch_bounds__(64) void scanB_kernel(const unsigned* __restrict__ bsum,
                                                   unsigned* __restrict__ boff, int nb) {
    int lane = threadIdx.x;
    unsigned v = (lane < nb) ? bsum[lane] : 0u;
    unsigned incl = v;
    #pragma unroll
    for (int off = 1; off < 64; off <<= 1) {
        unsigned t = __shfl_up(incl, off, 64);
        if (lane >= off) incl += t;
    }
    if (lane < nb) boff[lane] = incl - v;
}

__global__ __launch_bounds__(256) void scanC_kernel(const unsigned* __restrict__ cnt,
                                                    const unsigned* __restrict__ boff,
                                                    unsigned* __restrict__ outp, int N) {
    __shared__ unsigned wsum[4];
    int tid = threadIdx.x, wid = tid >> 6, lane = tid & 63;
    int base = blockIdx.x * SCAN_CHUNK + tid * 8;
    unsigned v[8];
    unsigned s = 0;
    bool act = base < N;
    if (act) {
        uint4 a = *(const uint4*)(cnt + base);
        uint4 b = *(const uint4*)(cnt + base + 4);
        v[0] = a.x; v[1] = a.y; v[2] = a.z; v[3] = a.w;
        v[4] = b.x; v[5] = b.y; v[6] = b.z; v[7] = b.w;
        #pragma unroll
        for (int j = 0; j < 8; ++j) s += v[j];
    }
    unsigned incl = s;
    #pragma unroll
    for (int off = 1; off < 64; off <<= 1) {
        unsigned t = __shfl_up(incl, off, 64);
        if (lane >= off) incl += t;
    }
    if (lane == 63) wsum[wid] = incl;
    __syncthreads();
    unsigned woff = 0;
    for (int w = 0; w < 4; ++w) if (w < wid) woff += wsum[w];
    if (act) {
        unsigned run = incl - s + woff + boff[blockIdx.x];
        #pragma unroll
        for (int j = 0; j < 8; ++j) {
            outp[base + j] = run;
            run += v[j];
        }
    }
}

// ---------------- pass 3: scatter edges bin-contiguously (LDS cursors, no global atomics) ----------------
__global__ __launch_bounds__(256) void binscatter_kernel(const int* __restrict__ src,
                                                         const int* __restrict__ dst,
                                                         const unsigned* __restrict__ offs,
                                                         unsigned* __restrict__ bedge, int E) {
    __shared__ unsigned lcur[NBIN];
    int tid = threadIdx.x;
    if (tid < NBIN) lcur[tid] = offs[tid * NB2 + blockIdx.x];
    __syncthreads();
    int e0 = blockIdx.x * BCHUNK;
    int e1 = min(e0 + BCHUNK, E);
    for (int e = e0 + tid; e < e1; e += 256) {
        int d = dst[e];
        int b = d >> 10;
        unsigned pos = atomicAdd(&lcur[b], 1u);
        bedge[pos] = ((unsigned)src[e] << 10) | (unsigned)(d & 1023);
    }
}

// ---------------- pass 4: per-bin node counts -> rowptr, dinv, csr placement ----------------
__global__ __launch_bounds__(256) void bucket_kernel(const unsigned* __restrict__ bedge,
                                                     const unsigned* __restrict__ offs,
                                                     float* __restrict__ dinv,
                                                     unsigned* __restrict__ rowptr,
                                                     unsigned* __restrict__ csr_src, int N) {
    __shared__ unsigned lcnt[1024];
    __shared__ unsigned lcur[1024];
    __shared__ unsigned wsum[4];
    int b = blockIdx.x;
    int tid = threadIdx.x, wid = tid >> 6, lane = tid & 63;
    unsigned ebeg = offs[b * NB2], eend = offs[(b + 1) * NB2];
    lcnt[tid] = 0; lcnt[tid + 256] = 0; lcnt[tid + 512] = 0; lcnt[tid + 768] = 0;
    __syncthreads();
    for (unsigned e = ebeg + tid; e < eend; e += 256)
        atomicAdd(&lcnt[bedge[e] & 1023], 1u);
    __syncthreads();
    unsigned c[4];
    unsigned s = 0;
    #pragma unroll
    for (int j = 0; j < 4; ++j) { c[j] = lcnt[tid * 4 + j]; s += c[j]; }
    unsigned incl = s;
    #pragma unroll
    for (int off = 1; off < 64; off <<= 1) {
        unsigned t = __shfl_up(incl, off, 64);
        if (lane >= off) incl += t;
    }
    if (lane == 63) wsum[wid] = incl;
    __syncthreads();
    unsigned woff = 0;
    for (int w = 0; w < 4; ++w) if (w < wid) woff += wsum[w];
    unsigned run = (incl - s) + woff + ebeg;
    int gbase = b * 1024 + tid * 4;
    #pragma unroll
    for (int j = 0; j < 4; ++j) {
        if (gbase + j < N) {
            rowptr[gbase + j] = run;
            dinv[gbase + j] = rsqrtf((float)c[j] + 1.0f);
        }
        lcur[tid * 4 + j] = run;
        run += c[j];
    }
    if (b == NBIN - 1 && tid == 0) rowptr[N] = eend;
    __syncthreads();
    for (unsigned e = ebeg + tid; e < eend; e += 256) {
        unsigned v = bedge[e];
        unsigned pos = atomicAdd(&lcur[v & 1023], 1u);
        csr_src[pos] = v >> 10;
    }
}

// ---------------- W -> lane-ordered bf16 MFMA fragments ----------------
__global__ __launch_bounds__(256) void wprep_kernel(const float* __restrict__ Ws,
                                                    short* __restrict__ Wf) {
    int l = blockIdx.x;
    for (int idx = threadIdx.x; idx < 16384; idx += 256) {
        int i = idx & 7;
        int lane = (idx >> 3) & 63;
        int ns = idx >> 9;
        int s = ns & 3, nt = ns >> 2;
        int k = s * 32 + (lane >> 4) * 8 + i;
        int n = nt * 16 + (lane & 15);
        Wf[l * 16384 + idx] = (short)f2bf(Ws[l * 16384 + k * NF + n]);
    }
}

// ---------------- H = X @ W via bf16 MFMA; C repacked through LDS -> uint4 stores ---------
template<bool L0>
__global__ __launch_bounds__(256) void gemm_mfma_kernel(const void* __restrict__ Xin,
                                                        const short* __restrict__ Wf,
                                                        ushort* __restrict__ Hb, int M) {
    __shared__ short Wl[16384];   // 32 KB: W fragments, then reused as the C tile
    int tid = threadIdx.x;
    for (int i = tid; i < 2048; i += 256)
        ((float4*)Wl)[i] = ((const float4*)Wf)[i];

    int wave = tid >> 6, lane = tid & 63;
    int r = lane & 15, kg = lane >> 4;
    int rowbase = blockIdx.x * 128 + wave * 32;

    bf16x8 afrag[2][4];
    #pragma unroll
    for (int t = 0; t < 2; ++t) {
        #pragma unroll
        for (int s = 0; s < 4; ++s) {
            int row = rowbase + t * 16 + r;
            if (row > M - 1) row = M - 1;
            if (L0) {
                const float* p = (const float*)Xin + (size_t)row * NF + s * 32 + kg * 8;
                float4 u0 = *(const float4*)p;
                float4 u1 = *(const float4*)(p + 4);
                bf16x8 a;
                a[0] = (short)f2bf(u0.x); a[1] = (short)f2bf(u0.y);
                a[2] = (short)f2bf(u0.z); a[3] = (short)f2bf(u0.w);
                a[4] = (short)f2bf(u1.x); a[5] = (short)f2bf(u1.y);
                a[6] = (short)f2bf(u1.z); a[7] = (short)f2bf(u1.w);
                afrag[t][s] = a;
            } else {
                afrag[t][s] = *(const bf16x8*)((const ushort*)Xin + (size_t)row * NF + s * 32 + kg * 8);
            }
        }
    }

    f32x4 acc[2][8];
    #pragma unroll
    for (int t = 0; t < 2; ++t)
        #pragma unroll
        for (int n = 0; n < 8; ++n)
            acc[t][n] = (f32x4){0.f, 0.f, 0.f, 0.f};

    __syncthreads();
    const bf16x8* WL = (const bf16x8*)Wl;
    #pragma unroll
    for (int s = 0; s < 4; ++s) {
        #pragma unroll
        for (int n = 0; n < 8; ++n) {
            bf16x8 bfr = WL[(n * 4 + s) * 64 + lane];
            acc[0][n] = __builtin_amdgcn_mfma_f32_16x16x32_bf16(afrag[0][s], bfr, acc[0][n], 0, 0, 0);
            acc[1][n] = __builtin_amdgcn_mfma_f32_16x16x32_bf16(afrag[1][s], bfr, acc[1][n], 0, 0, 0);
        }
    }

    // repack C through LDS (Wl is dead after the MFMA loop)
    __syncthreads();
    ushort* Cl = (ushort*)Wl;     // [128 rows][128 cols] bf16 = 32 KB
    int r4 = kg * 4;
    #pragma unroll
    for (int t = 0; t < 2; ++t) {
        #pragma unroll
        for (int n = 0; n < 8; ++n) {
            #pragma unroll
            for (int q = 0; q < 4; ++q) {
                Cl[(wave * 32 + t * 16 + r4 + q) * NF + n * 16 + r] = f2bf(acc[t][n][q]);
            }
        }
    }
    __syncthreads();
    // coalesced store: 2048 x 16B chunks; lane-consecutive chunks -> 1KB/wave-instr
    int row0 = blockIdx.x * 128;
    #pragma unroll
    for (int k = 0; k < 8; ++k) {
        int c = k * 256 + tid;
        int row = row0 + (c >> 4);
        if (row < M)
            ((uint4*)Hb)[(size_t)row * 16 + (c & 15)] = ((const uint4*)Cl)[c];
    }
}

// ---------------- aggregate: 16 lanes/node, 16B/lane (uint4 of 8 bf16), LDS=0 ----------
// 256 thr = 16 nodes/block; 6250 blocks exactly (no tail). 4-wide unroll (measured
// optimum: 8-wide raised VGPR 28->48, occupancy 66->48%, net loss).
__global__ __launch_bounds__(256) void aggregate_kernel(const ushort* __restrict__ Hb,
                                                        const float* __restrict__ dinv,
                                                        const unsigned* __restrict__ rowptr,
                                                        const unsigned* __restrict__ csr_src,
                                                        const float* __restrict__ bias,
                                                        ushort* __restrict__ Xout, int N) {
    int gid = blockIdx.x * 256 + threadIdx.x;
    int node = gid >> 4;
    int lane = gid & 15;
    int c0 = lane * 8;
    float di = dinv[node];
    float sl = di * di;
    float4 b0 = ((const float4*)bias)[lane * 2 + 0];
    float4 b1 = ((const float4*)bias)[lane * 2 + 1];
    uint4 hv = *(const uint4*)(Hb + (size_t)node * NF + c0);
    float a0, a1, a2, a3, a4, a5, a6, a7, t0, t1;
    up2(hv.x, t0, t1); a0 = fmaf(t0, sl, b0.x); a1 = fmaf(t1, sl, b0.y);
    up2(hv.y, t0, t1); a2 = fmaf(t0, sl, b0.z); a3 = fmaf(t1, sl, b0.w);
    up2(hv.z, t0, t1); a4 = fmaf(t0, sl, b1.x); a5 = fmaf(t1, sl, b1.y);
    up2(hv.w, t0, t1); a6 = fmaf(t0, sl, b1.z); a7 = fmaf(t1, sl, b1.w);
    unsigned e = rowptr[node], end = rowptr[node + 1];
    for (; e + 4 <= end; e += 4) {
        unsigned s0 = csr_src[e + 0], s1 = csr_src[e + 1];
        unsigned s2 = csr_src[e + 2], s3 = csr_src[e + 3];
        float n0 = dinv[s0] * di, n1 = dinv[s1] * di;
        float n2 = dinv[s2] * di, n3 = dinv[s3] * di;
        uint4 g0 = *(const uint4*)(Hb + (size_t)s0 * NF + c0);
        uint4 g1 = *(const uint4*)(Hb + (size_t)s1 * NF + c0);
        uint4 g2 = *(const uint4*)(Hb + (size_t)s2 * NF + c0);
        uint4 g3 = *(const uint4*)(Hb + (size_t)s3 * NF + c0);
        up2(g0.x, t0, t1); a0 = fmaf(t0, n0, a0); a1 = fmaf(t1, n0, a1);
        up2(g0.y, t0, t1); a2 = fmaf(t0, n0, a2); a3 = fmaf(t1, n0, a3);
        up2(g0.z, t0, t1); a4 = fmaf(t0, n0, a4); a5 = fmaf(t1, n0, a5);
        up2(g0.w, t0, t1); a6 = fmaf(t0, n0, a6); a7 = fmaf(t1, n0, a7);
        up2(g1.x, t0, t1); a0 = fmaf(t0, n1, a0); a1 = fmaf(t1, n1, a1);
        up2(g1.y, t0, t1); a2 = fmaf(t0, n1, a2); a3 = fmaf(t1, n1, a3);
        up2(g1.z, t0, t1); a4 = fmaf(t0, n1, a4); a5 = fmaf(t1, n1, a5);
        up2(g1.w, t0, t1); a6 = fmaf(t0, n1, a6); a7 = fmaf(t1, n1, a7);
        up2(g2.x, t0, t1); a0 = fmaf(t0, n2, a0); a1 = fmaf(t1, n2, a1);
        up2(g2.y, t0, t1); a2 = fmaf(t0, n2, a2); a3 = fmaf(t1, n2, a3);
        up2(g2.z, t0, t1); a4 = fmaf(t0, n2, a4); a5 = fmaf(t1, n2, a5);
        up2(g2.w, t0, t1); a6 = fmaf(t0, n2, a6); a7 = fmaf(t1, n2, a7);
        up2(g3.x, t0, t1); a0 = fmaf(t0, n3, a0); a1 = fmaf(t1, n3, a1);
        up2(g3.y, t0, t1); a2 = fmaf(t0, n3, a2); a3 = fmaf(t1, n3, a3);
        up2(g3.z, t0, t1); a4 = fmaf(t0, n3, a4); a5 = fmaf(t1, n3, a5);
        up2(g3.w, t0, t1); a6 = fmaf(t0, n3, a6); a7 = fmaf(t1, n3, a7);
    }
    for (; e < end; ++e) {
        unsigned s = csr_src[e];
        float nm = dinv[s] * di;
        uint4 g = *(const uint4*)(Hb + (size_t)s * NF + c0);
        up2(g.x, t0, t1); a0 = fmaf(t0, nm, a0); a1 = fmaf(t1, nm, a1);
        up2(g.y, t0, t1); a2 = fmaf(t0, nm, a2); a3 = fmaf(t1, nm, a3);
        up2(g.z, t0, t1); a4 = fmaf(t0, nm, a4); a5 = fmaf(t1, nm, a5);
        up2(g.w, t0, t1); a6 = fmaf(t0, nm, a6); a7 = fmaf(t1, nm, a7);
    }
    a0 = a0 > 0.f ? a0 : expm1f(a0);
    a1 = a1 > 0.f ? a1 : expm1f(a1);
    a2 = a2 > 0.f ? a2 : expm1f(a2);
    a3 = a3 > 0.f ? a3 : expm1f(a3);
    a4 = a4 > 0.f ? a4 : expm1f(a4);
    a5 = a5 > 0.f ? a5 : expm1f(a5);
    a6 = a6 > 0.f ? a6 : expm1f(a6);
    a7 = a7 > 0.f ? a7 : expm1f(a7);
    uint4 o;
    o.x = ((unsigned)f2bf(a1) << 16) | f2bf(a0);
    o.y = ((unsigned)f2bf(a3) << 16) | f2bf(a2);
    o.z = ((unsigned)f2bf(a5) << 16) | f2bf(a4);
    o.w = ((unsigned)f2bf(a7) << 16) | f2bf(a6);
    *(uint4*)(Xout + (size_t)node * NF + c0) = o;
}

// ---------------- last-layer aggregate with fused global max pool ----------------
// 16 nodes/block; 4 LDS slots (block spans >4 graphs essentially never at ~390
// nodes/graph); rare slot>=4 falls back to device-scope atomicMax on Gx.
__global__ __launch_bounds__(256) void aggregate_pool_kernel(const ushort* __restrict__ Hb,
                                                             const float* __restrict__ dinv,
                                                             const unsigned* __restrict__ rowptr,
                                                             const unsigned* __restrict__ csr_src,
                                                             const float* __restrict__ bias,
                                                             const int* __restrict__ batch,
                                                             unsigned* __restrict__ Gx, int N) {
    __shared__ unsigned lmax[4][NF];   // 2 KB
    __shared__ int g0s;
    int tid = threadIdx.x;
    int gid = blockIdx.x * 256 + tid;
    int node = gid >> 4;
    int lane = gid & 15;
    int c0 = lane * 8;
    for (int i = tid; i < 4 * NF; i += 256) ((unsigned*)lmax)[i] = 0;
    if (tid == 0) g0s = batch[blockIdx.x * 16];
    __syncthreads();
    float di = dinv[node];
    float sl = di * di;
    float4 b0 = ((const float4*)bias)[lane * 2 + 0];
    float4 b1 = ((const float4*)bias)[lane * 2 + 1];
    uint4 hv = *(const uint4*)(Hb + (size_t)node * NF + c0);
    float a0, a1, a2, a3, a4, a5, a6, a7, t0, t1;
    up2(hv.x, t0, t1); a0 = fmaf(t0, sl, b0.x); a1 = fmaf(t1, sl, b0.y);
    up2(hv.y, t0, t1); a2 = fmaf(t0, sl, b0.z); a3 = fmaf(t1, sl, b0.w);
    up2(hv.z, t0, t1); a4 = fmaf(t0, sl, b1.x); a5 = fmaf(t1, sl, b1.y);
    up2(hv.w, t0, t1); a6 = fmaf(t0, sl, b1.z); a7 = fmaf(t1, sl, b1.w);
    unsigned e = rowptr[node], end = rowptr[node + 1];
    for (; e + 4 <= end; e += 4) {
        unsigned s0 = csr_src[e + 0], s1 = csr_src[e + 1];
        unsigned s2 = csr_src[e + 2], s3 = csr_src[e + 3];
        float n0 = dinv[s0] * di, n1 = dinv[s1] * di;
        float n2 = dinv[s2] * di, n3 = dinv[s3] * di;
        uint4 g0 = *(const uint4*)(Hb + (size_t)s0 * NF + c0);
        uint4 g1 = *(const uint4*)(Hb + (size_t)s1 * NF + c0);
        uint4 g2 = *(const uint4*)(Hb + (size_t)s2 * NF + c0);
        uint4 g3 = *(const uint4*)(Hb + (size_t)s3 * NF + c0);
        up2(g0.x, t0, t1); a0 = fmaf(t0, n0, a0); a1 = fmaf(t1, n0, a1);
        up2(g0.y, t0, t1); a2 = fmaf(t0, n0, a2); a3 = fmaf(t1, n0, a3);
        up2(g0.z, t0, t1); a4 = fmaf(t0, n0, a4); a5 = fmaf(t1, n0, a5);
        up2(g0.w, t0, t1); a6 = fmaf(t0, n0, a6); a7 = fmaf(t1, n0, a7);
        up2(g1.x, t0, t1); a0 = fmaf(t0, n1, a0); a1 = fmaf(t1, n1, a1);
        up2(g1.y, t0, t1); a2 = fmaf(t0, n1, a2); a3 = fmaf(t1, n1, a3);
        up2(g1.z, t0, t1); a4 = fmaf(t0, n1, a4); a5 = fmaf(t1, n1, a5);
        up2(g1.w, t0, t1); a6 = fmaf(t0, n1, a6); a7 = fmaf(t1, n1, a7);
        up2(g2.x, t0, t1); a0 = fmaf(t0, n2, a0); a1 = fmaf(t1, n2, a1);
        up2(g2.y, t0, t1); a2 = fmaf(t0, n2, a2); a3 = fmaf(t1, n2, a3);
        up2(g2.z, t0, t1); a4 = fmaf(t0, n2, a4); a5 = fmaf(t1, n2, a5);
        up2(g2.w, t0, t1); a6 = fmaf(t0, n2, a6); a7 = fmaf(t1, n2, a7);
        up2(g3.x, t0, t1); a0 = fmaf(t0, n3, a0); a1 = fmaf(t1, n3, a1);
        up2(g3.y, t0, t1); a2 = fmaf(t0, n3, a2); a3 = fmaf(t1, n3, a3);
        up2(g3.z, t0, t1); a4 = fmaf(t0, n3, a4); a5 = fmaf(t1, n3, a5);
        up2(g3.w, t0, t1); a6 = fmaf(t0, n3, a6); a7 = fmaf(t1, n3, a7);
    }
    for (; e < end; ++e) {
        unsigned s = csr_src[e];
        float nm = dinv[s] * di;
        uint4 g = *(const uint4*)(Hb + (size_t)s * NF + c0);
        up2(g.x, t0, t1); a0 = fmaf(t0, nm, a0); a1 = fmaf(t1, nm, a1);
        up2(g.y, t0, t1); a2 = fmaf(t0, nm, a2); a3 = fmaf(t1, nm, a3);
        up2(g.z, t0, t1); a4 = fmaf(t0, nm, a4); a5 = fmaf(t1, nm, a5);
        up2(g.w, t0, t1); a6 = fmaf(t0, nm, a6); a7 = fmaf(t1, nm, a7);
    }
    a0 = a0 > 0.f ? a0 : expm1f(a0);
    a1 = a1 > 0.f ? a1 : expm1f(a1);
    a2 = a2 > 0.f ? a2 : expm1f(a2);
    a3 = a3 > 0.f ? a3 : expm1f(a3);
    a4 = a4 > 0.f ? a4 : expm1f(a4);
    a5 = a5 > 0.f ? a5 : expm1f(a5);
    a6 = a6 > 0.f ? a6 : expm1f(a6);
    a7 = a7 > 0.f ? a7 : expm1f(a7);
    int slot = batch[node] - g0s;
    if (slot < 4) {
        unsigned* lm = &lmax[slot][c0];
        atomicMax(lm + 0, fenc(a0)); atomicMax(lm + 1, fenc(a1));
        atomicMax(lm + 2, fenc(a2)); atomicMax(lm + 3, fenc(a3));
        atomicMax(lm + 4, fenc(a4)); atomicMax(lm + 5, fenc(a5));
        atomicMax(lm + 6, fenc(a6)); atomicMax(lm + 7, fenc(a7));
    } else {  // rare: block spans >4 graphs
        unsigned* gm = &Gx[(size_t)(g0s + slot) * NF + c0];
        atomicMax(gm + 0, fenc(a0)); atomicMax(gm + 1, fenc(a1));
        atomicMax(gm + 2, fenc(a2)); atomicMax(gm + 3, fenc(a3));
        atomicMax(gm + 4, fenc(a4)); atomicMax(gm + 5, fenc(a5));
        atomicMax(gm + 6, fenc(a6)); atomicMax(gm + 7, fenc(a7));
    }
    __syncthreads();
    for (int i = tid; i < 4 * NF; i += 256) {
        unsigned v = ((unsigned*)lmax)[i];
        if (v) atomicMax(&Gx[(size_t)(g0s + (i >> 7)) * NF + (i & (NF - 1))], v);
    }
}

// ---------------- classifier: softmax(decode(Gx) @ Wc + bc), fp32 ----------------
__global__ __launch_bounds__(128) void classify_kernel(const unsigned* __restrict__ Gx,
                                                       const float* __restrict__ Wc,
                                                       const float* __restrict__ bc,
                                                       float* __restrict__ out) {
    __shared__ float gr[NF];
    __shared__ float lg[NCLASSES];
    int g = blockIdx.x;
    int tid = threadIdx.x;
    gr[tid] = fdec(Gx[(size_t)g * NF + tid]);
    __syncthreads();
    if (tid < NCLASSES) {
        float s = bc[tid];
        for (int k = 0; k < NF; ++k) s = fmaf(gr[k], Wc[k * NCLASSES + tid], s);
        lg[tid] = s;
    }
    __syncthreads();
    if (tid == 0) {
        float m = lg[0];
        #pragma unroll
        for (int c = 1; c < NCLASSES; ++c) m = fmaxf(m, lg[c]);
        float e[NCLASSES];
        float sum = 0.f;
        #pragma unroll
        for (int c = 0; c < NCLASSES; ++c) { e[c] = expf(lg[c] - m); sum += e[c]; }
        #pragma unroll
        for (int c = 0; c < NCLASSES; ++c) out[g * NCLASSES + c] = e[c] / sum;
    }
}

extern "C" void kernel_launch(void* const* d_in, const int* in_sizes, int n_in,
                              void* d_out, int out_size, void* d_ws, size_t ws_size,
                              hipStream_t stream) {
    const float* x     = (const float*)d_in[0];
    const int*   ei    = (const int*)d_in[1];
    const int*   batch = (const int*)d_in[2];
    const float* Ws    = (const float*)d_in[3];
    const float* bs    = (const float*)d_in[4];
    const float* Wc    = (const float*)d_in[5];
    const float* bc    = (const float*)d_in[6];
    float* out = (float*)d_out;

    const int* src = ei;
    const int* dst = ei + NEDGES;

    char* ws = (char*)d_ws;
    size_t off = 0;
    auto alloc = [&](size_t bytes) -> void* {
        off = (off + 255) & ~(size_t)255;
        void* p = ws + off;
        off += bytes;
        return p;
    };
    ushort*   B0      = (ushort*)alloc(sizeof(ushort) * (size_t)NNODES * NF);
    ushort*   B1      = (ushort*)alloc(sizeof(ushort) * (size_t)NNODES * NF);
    ushort*   Hb      = (ushort*)alloc(sizeof(ushort) * (size_t)NNODES * NF);
    float*    dinvp   = (float*)alloc(sizeof(float) * NNODES);
    unsigned* rowptr  = (unsigned*)alloc(sizeof(unsigned) * (NNODES + 1));
    unsigned* csr_src = (unsigned*)alloc(sizeof(unsigned) * NEDGES);
    unsigned* bedge   = (unsigned*)alloc(sizeof(unsigned) * NEDGES);
    unsigned* offs    = (unsigned*)alloc(sizeof(unsigned) * (CNTS_PAD + 1));
    unsigned* bsum    = (unsigned*)alloc(sizeof(unsigned) * 16);
    unsigned* boff    = (unsigned*)alloc(sizeof(unsigned) * 16);
    short*    Wf      = (short*)alloc(sizeof(short) * 3 * 16384);
    unsigned* cnts    = (unsigned*)alloc(sizeof(unsigned) * CNTS_PAD);
    unsigned* Gx      = (unsigned*)alloc(sizeof(unsigned) * NGRAPHS * NF);

    // no memset: binct_kernel zeroes the cnts pad + Gx (stream-ordered before use)
    wprep_kernel<<<3, 256, 0, stream>>>(Ws, Wf);
    binct_kernel<<<NB2, 256, 0, stream>>>(dst, cnts, Gx, NEDGES);
    scanA_kernel<<<CNTS_PAD / SCAN_CHUNK, 256, 0, stream>>>(cnts, bsum, CNTS_PAD);
    scanB_kernel<<<1, 64, 0, stream>>>(bsum, boff, CNTS_PAD / SCAN_CHUNK);
    scanC_kernel<<<CNTS_PAD / SCAN_CHUNK, 256, 0, stream>>>(cnts, boff, offs, CNTS_PAD);
    binscatter_kernel<<<NB2, 256, 0, stream>>>(src, dst, offs, bedge, NEDGES);
    bucket_kernel<<<NBIN, 256, 0, stream>>>(bedge, offs, dinvp, rowptr, csr_src, NNODES);

    int gemm_grid = (NNODES + 127) / 128;   // 782
    int agg_grid  = NNODES / 16;            // 6250 exact (16 nodes/block, 16 lanes/node)

    gemm_mfma_kernel<true><<<gemm_grid, 256, 0, stream>>>(x, Wf + 0 * 16384, Hb, NNODES);
    aggregate_kernel<<<agg_grid, 256, 0, stream>>>(Hb, dinvp, rowptr, csr_src,
                                                   bs + 0 * NF, B1, NNODES);
    gemm_mfma_kernel<false><<<gemm_grid, 256, 0, stream>>>(B1, Wf + 1 * 16384, Hb, NNODES);
    aggregate_kernel<<<agg_grid, 256, 0, stream>>>(Hb, dinvp, rowptr, csr_src,
                                                   bs + 1 * NF, B0, NNODES);
    gemm_mfma_kernel<false><<<gemm_grid, 256, 0, stream>>>(B0, Wf + 2 * 16384, Hb, NNODES);
    aggregate_pool_kernel<<<agg_grid, 256, 0, stream>>>(Hb, dinvp, rowptr, csr_src,
                                                        bs + 2 * NF, batch, Gx, NNODES);

    classify_kernel<<<NGRAPHS, 128, 0, stream>>>(Gx, Wc, bc, out);
}